// Round 1
// baseline (158.119 us; speedup 1.0000x reference)
//
#include <hip/hip_runtime.h>
#include <hip/hip_bf16.h>
#include <math.h>

// SpectralConv2d (FNO): B=16, Cin=Cout=32, H=W=256, MODES=16x16.
// Strategy: partial DFTs instead of full FFT2.
//   kA : T[b,i,m,w]   = sum_h x[b,i,h,w] * e^{-2pi i m h/256}        (m<16)
//   kB1: xsub[b,i,m,n]= sum_w T[b,i,m,w] * e^{-2pi i n w/256}        (n<16)
//   kB2: osub[b,o,m,n]= sum_i xsub[b,i,m,n] * (wr+i*wi)[i,o,m,n]
//   kCD: U[m,w] = sum_n osub[m,n] e^{+2pi i n w/256};
//        y[b,o,h,w] = (1/65536) * Re( sum_m U[m,w] e^{+2pi i m h/256} )

#define PI_F 3.14159265358979323846f

__global__ __launch_bounds__(256) void kA(const float* __restrict__ x,
                                          float2* __restrict__ T) {
    __shared__ float2 tw[256];
    const int t = threadIdx.x;
    {
        float ang = (2.0f * PI_F / 256.0f) * (float)t;
        tw[t] = make_float2(__cosf(ang), __sinf(ang));
    }
    __syncthreads();

    const int bi = blockIdx.x;                 // b*Cin + i  (0..511)
    const float* xp = x + (size_t)bi * 65536;  // [h][w]
    const int w = t;

    float Tr[16], Ti[16];
#pragma unroll
    for (int m = 0; m < 16; ++m) { Tr[m] = 0.0f; Ti[m] = 0.0f; }

    // radix-2 over h: pair (h, h+128); even m use x[h]+x[h+128], odd m the difference
    for (int h = 0; h < 128; ++h) {
        float x0 = xp[h * 256 + w];
        float x1 = xp[(h + 128) * 256 + w];
        float xe = x0 + x1;
        float xo = x0 - x1;
#pragma unroll
        for (int m = 0; m < 16; ++m) {
            int idx = (m * h) & 255;          // uniform across wave -> LDS broadcast
            float2 cs = tw[idx];
            float xv = (m & 1) ? xo : xe;
            Tr[m] = fmaf(xv, cs.x, Tr[m]);    // e^{-i a} = (c, -s)
            Ti[m] = fmaf(-xv, cs.y, Ti[m]);
        }
    }

    float2* Tp = T + (size_t)bi * (16 * 256);
#pragma unroll
    for (int m = 0; m < 16; ++m) Tp[m * 256 + w] = make_float2(Tr[m], Ti[m]);
}

__global__ __launch_bounds__(256) void kB1(const float2* __restrict__ T,
                                           float2* __restrict__ xsub) {
    __shared__ float2 tw[256];
    __shared__ float2 Ts[16 * 256];           // 32 KB
    const int t = threadIdx.x;
    {
        float ang = (2.0f * PI_F / 256.0f) * (float)t;
        tw[t] = make_float2(__cosf(ang), __sinf(ang));
    }
    const int bi = blockIdx.x;
    const float2* Tp = T + (size_t)bi * 4096;
    for (int k = t; k < 4096; k += 256) Ts[k] = Tp[k];
    __syncthreads();

    const int m = t >> 4;
    const int n = t & 15;
    float ar = 0.0f, ai = 0.0f;
    for (int w2 = 0; w2 < 256; ++w2) {
        float2 Tv = Ts[m * 256 + w2];
        float2 cs = tw[(n * w2) & 255];
        // (Tr + i Ti) * (c - i s)
        ar += Tv.x * cs.x + Tv.y * cs.y;
        ai += Tv.y * cs.x - Tv.x * cs.y;
    }
    xsub[(size_t)bi * 256 + t] = make_float2(ar, ai);
}

__global__ __launch_bounds__(256) void kB2(const float2* __restrict__ xsub,
                                           const float* __restrict__ wr,
                                           const float* __restrict__ wi,
                                           float2* __restrict__ osub) {
    const int bo = blockIdx.x;                // b*32 + o
    const int b = bo >> 5;
    const int o = bo & 31;
    const int mn = threadIdx.x;
    float ar = 0.0f, ai = 0.0f;
#pragma unroll 4
    for (int i = 0; i < 32; ++i) {
        float2 xv = xsub[(size_t)(b * 32 + i) * 256 + mn];
        float wre = wr[(size_t)(i * 32 + o) * 256 + mn];
        float wim = wi[(size_t)(i * 32 + o) * 256 + mn];
        ar += xv.x * wre - xv.y * wim;
        ai += xv.x * wim + xv.y * wre;
    }
    osub[(size_t)bo * 256 + mn] = make_float2(ar, ai);
}

__global__ __launch_bounds__(256) void kCD(const float2* __restrict__ osub,
                                           float* __restrict__ y) {
    __shared__ float2 tw[256];
    __shared__ float2 os[256];
    const int t = threadIdx.x;
    {
        float ang = (2.0f * PI_F / 256.0f) * (float)t;
        tw[t] = make_float2(__cosf(ang), __sinf(ang));
    }
    const int bo = blockIdx.x;                // b*32 + o
    os[t] = osub[(size_t)bo * 256 + t];
    __syncthreads();

    const int w = t;
    // inverse twiddles over n for this column
    float twr[16], twi[16];
#pragma unroll
    for (int n = 0; n < 16; ++n) {
        float2 cs = tw[(n * w) & 255];
        twr[n] = cs.x; twi[n] = cs.y;
    }
    // U[m] = sum_n os[m][n] * (c + i s)
    float Ur[16], Ui[16];
#pragma unroll
    for (int m = 0; m < 16; ++m) {
        float ur = 0.0f, ui = 0.0f;
#pragma unroll
        for (int n = 0; n < 16; ++n) {
            float2 ov = os[m * 16 + n];       // uniform -> broadcast
            ur += ov.x * twr[n] - ov.y * twi[n];
            ui += ov.x * twi[n] + ov.y * twr[n];
        }
        Ur[m] = ur; Ui[m] = ui;
    }

    float* yp = y + (size_t)bo * 65536;
    const float inv = 1.0f / 65536.0f;
    // radix-2 over h: y[h] = ae+ao, y[h+128] = ae-ao
    for (int h = 0; h < 128; ++h) {
        float ae = 0.0f, ao = 0.0f;
#pragma unroll
        for (int m = 0; m < 16; ++m) {
            float2 cs = tw[(m * h) & 255];    // uniform -> broadcast
            float v = fmaf(Ur[m], cs.x, -Ui[m] * cs.y);  // Re(U * e^{+i a})
            if (m & 1) ao += v; else ae += v;
        }
        yp[h * 256 + w] = (ae + ao) * inv;
        yp[(h + 128) * 256 + w] = (ae - ao) * inv;
    }
}

extern "C" void kernel_launch(void* const* d_in, const int* in_sizes, int n_in,
                              void* d_out, int out_size, void* d_ws, size_t ws_size,
                              hipStream_t stream) {
    const float* x  = (const float*)d_in[0];   // [16][32][256][256]
    const float* wr = (const float*)d_in[1];   // [32][32][16][16]
    const float* wi = (const float*)d_in[2];   // [32][32][16][16]
    float* y = (float*)d_out;                  // [16][32][256][256]

    char* ws = (char*)d_ws;
    float2* T    = (float2*)(ws);                        // 512*16*256*8  = 16 MB
    float2* xsub = (float2*)(ws + (size_t)16777216);     // 512*256*8     =  1 MB
    float2* osub = (float2*)(ws + (size_t)17825792);     // 512*256*8     =  1 MB

    kA <<<512, 256, 0, stream>>>(x, T);
    kB1<<<512, 256, 0, stream>>>(T, xsub);
    kB2<<<512, 256, 0, stream>>>(xsub, wr, wi, osub);
    kCD<<<512, 256, 0, stream>>>(osub, y);
}

// Round 2
// 100.112 us; speedup vs baseline: 1.5794x; 1.5794x over previous
//
#include <hip/hip_runtime.h>
#include <hip/hip_bf16.h>
#include <math.h>

// SpectralConv2d (FNO): B=16, Cin=Cout=32, H=W=256, MODES=16x16.
// Partial DFTs; "fat" waves: each lane owns 4 w-columns so twiddle
// broadcasts amortize 4x and each wave has 8 coalesced loads in flight.

#define PI_F 3.14159265358979323846f

// kA: T[bi][m][w] = sum_h x[bi][h][w] e^{-2pi i m h/256}, m<16
__global__ __launch_bounds__(256, 2) void kA(const float* __restrict__ x,
                                             float2* __restrict__ T) {
    __shared__ float2 tw[256];
    __shared__ float2 red[4][16][128];   // 64 KB reduce buffer (2 passes)
    const int t = threadIdx.x;
    { float ang = (2.0f * PI_F / 256.0f) * (float)t;
      tw[t] = make_float2(__cosf(ang), __sinf(ang)); }
    __syncthreads();

    const int bi = blockIdx.x;
    const float* xp = x + (size_t)bi * 65536;
    const int l = t & 63, wv = t >> 6;   // lane-w, wave = h-chunk

    float Tr[4][16], Ti[4][16];
#pragma unroll
    for (int c = 0; c < 4; ++c)
#pragma unroll
        for (int m = 0; m < 16; ++m) { Tr[c][m] = 0.0f; Ti[c][m] = 0.0f; }

#pragma unroll 2
    for (int j = 0; j < 32; ++j) {
        const int h = wv * 32 + j;       // h-pair (h, h+128)
        float xe[4], xo[4];
#pragma unroll
        for (int c = 0; c < 4; ++c) {
            float x0 = xp[h * 256 + c * 64 + l];
            float x1 = xp[(h + 128) * 256 + c * 64 + l];
            xe[c] = x0 + x1; xo[c] = x0 - x1;
        }
#pragma unroll
        for (int m = 0; m < 16; ++m) {
            float2 cs = tw[(m * h) & 255];      // wave-uniform -> broadcast
#pragma unroll
            for (int c = 0; c < 4; ++c) {
                float xv = (m & 1) ? xo[c] : xe[c];
                Tr[c][m] = fmaf(xv, cs.x, Tr[c][m]);   // e^{-ia} = (c,-s)
                Ti[c][m] = fmaf(-xv, cs.y, Ti[c][m]);
            }
        }
    }

    // cross-wave reduce (4 h-chunks), two passes of 2 columns each
    float2* Tp = T + (size_t)bi * 4096;
#pragma unroll
    for (int pass = 0; pass < 2; ++pass) {
        if (pass) __syncthreads();
#pragma unroll
        for (int c2 = 0; c2 < 2; ++c2) {
            int c = pass * 2 + c2;
#pragma unroll
            for (int m = 0; m < 16; ++m)
                red[wv][m][c2 * 64 + l] = make_float2(Tr[c][m], Ti[c][m]);
        }
        __syncthreads();
        const int w = t & 127, mg = t >> 7;
#pragma unroll
        for (int j = 0; j < 8; ++j) {
            int m = mg * 8 + j;
            float2 a0 = red[0][m][w], a1 = red[1][m][w];
            float2 a2 = red[2][m][w], a3 = red[3][m][w];
            Tp[m * 256 + pass * 128 + w] =
                make_float2(a0.x + a1.x + a2.x + a3.x, a0.y + a1.y + a2.y + a3.y);
        }
    }
}

// kB1: xsub[bi][m][n] = sum_w T[bi][m][w] e^{-2pi i n w/256}
// twiddle via in-register complex rotation (no LDS reads for twiddles)
__global__ __launch_bounds__(256) void kB1(const float2* __restrict__ T,
                                           float2* __restrict__ xsub) {
    __shared__ float2 Ts[16 * 257];      // padded rows: conflict-free m-banks
    const int t = threadIdx.x;
    const int bi = blockIdx.x;
    const float2* Tp = T + (size_t)bi * 4096;
    for (int k = t; k < 4096; k += 256) Ts[(k >> 8) * 257 + (k & 255)] = Tp[k];
    __syncthreads();

    const int m = t >> 4, n = t & 15;
    float ang = (2.0f * PI_F / 256.0f) * (float)n;
    float c1 = __cosf(ang), s1 = __sinf(ang);
    float cr = 1.0f, ci = 0.0f;          // rotates to (cos nw, sin nw)
    float ar = 0.0f, ai = 0.0f;
    for (int w2 = 0; w2 < 256; ++w2) {
        float2 Tv = Ts[m * 257 + w2];
        ar += Tv.x * cr + Tv.y * ci;     // * e^{-i a}
        ai += Tv.y * cr - Tv.x * ci;
        float nr = cr * c1 - ci * s1;
        float nc = cr * s1 + ci * c1;
        cr = nr; ci = nc;
    }
    xsub[(size_t)bi * 256 + t] = make_float2(ar, ai);
}

// kB2: osub[b][o][mn] = sum_i xsub[b][i][mn] * (wr + i wi)[i][o][mn]
__global__ __launch_bounds__(256) void kB2(const float2* __restrict__ xsub,
                                           const float* __restrict__ wr,
                                           const float* __restrict__ wi,
                                           float2* __restrict__ osub) {
    const int bo = blockIdx.x;
    const int b = bo >> 5;
    const int o = bo & 31;
    const int mn = threadIdx.x;
    float ar = 0.0f, ai = 0.0f;
#pragma unroll 4
    for (int i = 0; i < 32; ++i) {
        float2 xv = xsub[(size_t)(b * 32 + i) * 256 + mn];
        float wre = wr[(size_t)(i * 32 + o) * 256 + mn];
        float wim = wi[(size_t)(i * 32 + o) * 256 + mn];
        ar += xv.x * wre - xv.y * wim;
        ai += xv.x * wim + xv.y * wre;
    }
    osub[(size_t)bo * 256 + mn] = make_float2(ar, ai);
}

// kCD: U[m][w] = sum_n osub[m][n] e^{+2pi i n w/256};
//      y[h][w] = (1/65536) Re( sum_m U[m][w] e^{+2pi i m h/256} )
__global__ __launch_bounds__(256, 2) void kCD(const float2* __restrict__ osub,
                                              float* __restrict__ y) {
    __shared__ float2 tw[256];
    __shared__ float2 os[256];
    __shared__ float2 U[16][256];        // 32 KB
    const int t = threadIdx.x;
    { float ang = (2.0f * PI_F / 256.0f) * (float)t;
      tw[t] = make_float2(__cosf(ang), __sinf(ang)); }
    const int bo = blockIdx.x;
    os[t] = osub[(size_t)bo * 256 + t];
    __syncthreads();

    // cooperative U: thread t computes column w = t for all m
    {
        float twr[16], twi[16];
#pragma unroll
        for (int n = 0; n < 16; ++n) {
            float2 cs = tw[(n * t) & 255];
            twr[n] = cs.x; twi[n] = cs.y;
        }
#pragma unroll
        for (int m = 0; m < 16; ++m) {
            float ur = 0.0f, ui = 0.0f;
#pragma unroll
            for (int n = 0; n < 16; ++n) {
                float2 ov = os[m * 16 + n];          // uniform -> broadcast
                ur += ov.x * twr[n] - ov.y * twi[n]; // * e^{+i a}
                ui += ov.x * twi[n] + ov.y * twr[n];
            }
            U[m][t] = make_float2(ur, ui);
        }
    }
    __syncthreads();

    const int l = t & 63, wv = t >> 6;
    float Ur[4][16], Ui[4][16];
#pragma unroll
    for (int c = 0; c < 4; ++c)
#pragma unroll
        for (int m = 0; m < 16; ++m) {
            float2 u = U[m][c * 64 + l];
            Ur[c][m] = u.x; Ui[c][m] = u.y;
        }

    float* yp = y + (size_t)bo * 65536;
    const float inv = 1.0f / 65536.0f;
#pragma unroll 2
    for (int j = 0; j < 32; ++j) {
        const int h = wv * 32 + j;       // h-pair (h, h+128)
        float ae[4] = {0, 0, 0, 0}, ao[4] = {0, 0, 0, 0};
#pragma unroll
        for (int m = 0; m < 16; ++m) {
            float2 cs = tw[(m * h) & 255];          // uniform -> broadcast
#pragma unroll
            for (int c = 0; c < 4; ++c) {
                float v = Ur[c][m] * cs.x - Ui[c][m] * cs.y;  // Re(U e^{+ia})
                if (m & 1) ao[c] += v; else ae[c] += v;
            }
        }
#pragma unroll
        for (int c = 0; c < 4; ++c) {
            yp[h * 256 + c * 64 + l]         = (ae[c] + ao[c]) * inv;
            yp[(h + 128) * 256 + c * 64 + l] = (ae[c] - ao[c]) * inv;
        }
    }
}

extern "C" void kernel_launch(void* const* d_in, const int* in_sizes, int n_in,
                              void* d_out, int out_size, void* d_ws, size_t ws_size,
                              hipStream_t stream) {
    const float* x  = (const float*)d_in[0];   // [16][32][256][256]
    const float* wr = (const float*)d_in[1];   // [32][32][16][16]
    const float* wi = (const float*)d_in[2];   // [32][32][16][16]
    float* y = (float*)d_out;                  // [16][32][256][256]

    char* ws = (char*)d_ws;
    float2* T    = (float2*)(ws);                        // 512*16*256*8 = 16 MB
    float2* xsub = (float2*)(ws + (size_t)16777216);     // 1 MB
    float2* osub = (float2*)(ws + (size_t)17825792);     // 1 MB

    kA <<<512, 256, 0, stream>>>(x, T);
    kB1<<<512, 256, 0, stream>>>(T, xsub);
    kB2<<<512, 256, 0, stream>>>(xsub, wr, wi, osub);
    kCD<<<512, 256, 0, stream>>>(osub, y);
}

// Round 3
// 79.021 us; speedup vs baseline: 2.0010x; 1.2669x over previous
//
#include <hip/hip_runtime.h>
#include <hip/hip_bf16.h>
#include <math.h>

// SpectralConv2d (FNO): B=16, Cin=Cout=32, H=W=256, MODES=16x16.
// Two fused kernels:
//  kF (per b,i): T[m][w] = sum_h x[h][w] e^{-2pi i m h/256} (radix-2 over h,
//                LDS-resident), then xsub[m][n] = sum_w T[m][w] e^{-2pi i n w/256}
//  kI (per b,o): os[m][n] = sum_i xsub[b,i,m,n]*W[i,o,m,n];
//                U[m][w] = sum_n os[m][n] e^{+2pi i n w/256};
//                y[h][w] = (1/65536) Re(sum_m U[m][w] e^{+2pi i m h/256})
// Lane owns w = 4l..4l+3 so x/y move as float4 (1 KB per wave per VMEM instr).

#define PI_F 3.14159265358979323846f

__global__ __launch_bounds__(256, 2) void kF(const float* __restrict__ x,
                                             float2* __restrict__ xsub) {
    __shared__ float2 tw[256];
    __shared__ float2 red[4][4][4][64];   // [wave][m'][c][lane]   32 KB
    __shared__ float2 Ts[16][4][65];      // [m][c][lane], padded  33 KB
    const int t = threadIdx.x;
    { float ang = (2.0f * PI_F / 256.0f) * (float)t;
      tw[t] = make_float2(__cosf(ang), __sinf(ang)); }
    __syncthreads();

    const int bi = blockIdx.x;
    const float* xp = x + (size_t)bi * 65536;
    const int l = t & 63, wv = t >> 6;    // lane (w-group), wave (h-chunk)

    float Tr[4][16], Ti[4][16];
#pragma unroll
    for (int c = 0; c < 4; ++c)
#pragma unroll
        for (int m = 0; m < 16; ++m) { Tr[c][m] = 0.0f; Ti[c][m] = 0.0f; }

#pragma unroll 2
    for (int j = 0; j < 32; ++j) {
        const int h = wv * 32 + j;        // h-pair (h, h+128)
        const float4 v0 = ((const float4*)(xp + h * 256))[l];
        const float4 v1 = ((const float4*)(xp + (h + 128) * 256))[l];
        const float xe[4] = {v0.x + v1.x, v0.y + v1.y, v0.z + v1.z, v0.w + v1.w};
        const float xo[4] = {v0.x - v1.x, v0.y - v1.y, v0.z - v1.z, v0.w - v1.w};
#pragma unroll
        for (int m = 0; m < 16; ++m) {
            float2 cs = tw[(m * h) & 255];          // wave-uniform -> broadcast
#pragma unroll
            for (int c = 0; c < 4; ++c) {
                float xv = (m & 1) ? xo[c] : xe[c];
                Tr[c][m] = fmaf(xv, cs.x, Tr[c][m]); // e^{-ia} = (cos, -sin)
                Ti[c][m] = fmaf(-xv, cs.y, Ti[c][m]);
            }
        }
    }

    // cross-wave reduce into Ts, 4 m-groups of 4
#pragma unroll
    for (int mg = 0; mg < 4; ++mg) {
        if (mg) __syncthreads();
#pragma unroll
        for (int mm = 0; mm < 4; ++mm)
#pragma unroll
            for (int c = 0; c < 4; ++c)
                red[wv][mm][c][l] = make_float2(Tr[c][mg * 4 + mm], Ti[c][mg * 4 + mm]);
        __syncthreads();
        const int mq = t >> 6, idx = t & 63;
#pragma unroll
        for (int c = 0; c < 4; ++c) {
            float2 a0 = red[0][mq][c][idx], a1 = red[1][mq][c][idx];
            float2 a2 = red[2][mq][c][idx], a3 = red[3][mq][c][idx];
            Ts[mg * 4 + mq][c][idx] =
                make_float2(a0.x + a1.x + a2.x + a3.x, a0.y + a1.y + a2.y + a3.y);
        }
    }
    __syncthreads();

    // w-DFT: thread t -> (m = t>>4, n = t&15); rotation recurrence twiddles
    const int m = t >> 4, n = t & 15;
    float ang = (2.0f * PI_F / 256.0f) * (float)n;
    float c1 = __cosf(ang), s1 = __sinf(ang);
    float cr = 1.0f, ci = 0.0f;
    float ar = 0.0f, ai = 0.0f;
    for (int w2 = 0; w2 < 256; ++w2) {
        float2 Tv = Ts[m][w2 & 3][w2 >> 2];          // 4 addrs/wave, distinct banks
        ar += Tv.x * cr + Tv.y * ci;                 // * e^{-i n w}
        ai += Tv.y * cr - Tv.x * ci;
        float nr = fmaf(cr, c1, -ci * s1);
        float nc = fmaf(cr, s1, ci * c1);
        cr = nr; ci = nc;
    }
    xsub[(size_t)bi * 256 + t] = make_float2(ar, ai);
}

__global__ __launch_bounds__(256, 2) void kI(const float2* __restrict__ xsub,
                                             const float* __restrict__ wr,
                                             const float* __restrict__ wi,
                                             float* __restrict__ y) {
    __shared__ float2 tw[256];
    __shared__ float2 os[256];
    __shared__ float2 U[16][256];         // 32 KB
    const int t = threadIdx.x;
    { float ang = (2.0f * PI_F / 256.0f) * (float)t;
      tw[t] = make_float2(__cosf(ang), __sinf(ang)); }

    const int bo = blockIdx.x, b = bo >> 5, o = bo & 31;

    // stage 1: channel mix (xsub, weights stream from L2/L3)
    {
        float ar = 0.0f, ai = 0.0f;
#pragma unroll 4
        for (int i = 0; i < 32; ++i) {
            float2 xv = xsub[(size_t)(b * 32 + i) * 256 + t];
            float wre = wr[(size_t)(i * 32 + o) * 256 + t];
            float wim = wi[(size_t)(i * 32 + o) * 256 + t];
            ar += xv.x * wre - xv.y * wim;
            ai += xv.x * wim + xv.y * wre;
        }
        os[t] = make_float2(ar, ai);
    }
    __syncthreads();

    // stage 2: cooperative U: thread t = column w
    {
        float twr[16], twi[16];
#pragma unroll
        for (int n = 0; n < 16; ++n) {
            float2 cs = tw[(n * t) & 255];
            twr[n] = cs.x; twi[n] = cs.y;
        }
#pragma unroll
        for (int m = 0; m < 16; ++m) {
            float ur = 0.0f, ui = 0.0f;
#pragma unroll
            for (int n = 0; n < 16; ++n) {
                float2 ov = os[m * 16 + n];          // uniform -> broadcast
                ur += ov.x * twr[n] - ov.y * twi[n]; // * e^{+i n w}
                ui += ov.x * twi[n] + ov.y * twr[n];
            }
            U[m][t] = make_float2(ur, ui);
        }
    }
    __syncthreads();

    // stage 3: inverse h-DFT, radix-2 over h, float4 stores
    const int l = t & 63, wv = t >> 6;
    float Ur[4][16], Ui[4][16];
#pragma unroll
    for (int m = 0; m < 16; ++m) {
        const float4* Um = (const float4*)&U[m][0];
        float4 p0 = Um[2 * l], p1 = Um[2 * l + 1];
        Ur[0][m] = p0.x; Ui[0][m] = p0.y; Ur[1][m] = p0.z; Ui[1][m] = p0.w;
        Ur[2][m] = p1.x; Ui[2][m] = p1.y; Ur[3][m] = p1.z; Ui[3][m] = p1.w;
    }

    float* yp = y + (size_t)bo * 65536;
    const float inv = 1.0f / 65536.0f;
#pragma unroll 2
    for (int j = 0; j < 32; ++j) {
        const int h = wv * 32 + j;        // h-pair (h, h+128)
        float ae[4] = {0, 0, 0, 0}, ao[4] = {0, 0, 0, 0};
#pragma unroll
        for (int m = 0; m < 16; ++m) {
            float2 cs = tw[(m * h) & 255];           // uniform -> broadcast
#pragma unroll
            for (int c = 0; c < 4; ++c) {
                float v = fmaf(Ur[c][m], cs.x, -Ui[c][m] * cs.y); // Re(U e^{+ia})
                if (m & 1) ao[c] += v; else ae[c] += v;
            }
        }
        float4 ye, yo2;
        ye.x = (ae[0] + ao[0]) * inv; ye.y = (ae[1] + ao[1]) * inv;
        ye.z = (ae[2] + ao[2]) * inv; ye.w = (ae[3] + ao[3]) * inv;
        yo2.x = (ae[0] - ao[0]) * inv; yo2.y = (ae[1] - ao[1]) * inv;
        yo2.z = (ae[2] - ao[2]) * inv; yo2.w = (ae[3] - ao[3]) * inv;
        ((float4*)(yp + h * 256))[l] = ye;
        ((float4*)(yp + (h + 128) * 256))[l] = yo2;
    }
}

extern "C" void kernel_launch(void* const* d_in, const int* in_sizes, int n_in,
                              void* d_out, int out_size, void* d_ws, size_t ws_size,
                              hipStream_t stream) {
    const float* x  = (const float*)d_in[0];   // [16][32][256][256]
    const float* wr = (const float*)d_in[1];   // [32][32][16][16]
    const float* wi = (const float*)d_in[2];   // [32][32][16][16]
    float* y = (float*)d_out;                  // [16][32][256][256]

    float2* xsub = (float2*)d_ws;              // 512*256*8 = 1 MB

    kF<<<512, 256, 0, stream>>>(x, xsub);
    kI<<<512, 256, 0, stream>>>(xsub, wr, wi, y);
}